// Round 2
// baseline (443.235 us; speedup 1.0000x reference)
//
#include <hip/hip_runtime.h>

#define N_NODES 100000
#define N_EDGES 3200000
#define HD      32
#define NLAYERS 4
#define NGRAPHS 1000
#define BN_EPS  1e-5f
#define BSHIFT  9                         // 512-node buckets
#define NBUCK   ((N_NODES + 511) >> 9)    // 196
#define PCHUNK  8192                      // edges per partition block
#define NPB     ((N_EDGES + PCHUNK - 1) / PCHUNK)   // 391
#define ZBLOCKS ((NGRAPHS * HD + 255) / 256)        // 125

typedef _Float16 f16;
typedef _Float16 f16x8 __attribute__((ext_vector_type(8)));
typedef float    f32x4 __attribute__((ext_vector_type(4)));
typedef int      i32x4 __attribute__((ext_vector_type(4)));
typedef unsigned int  u32x2 __attribute__((ext_vector_type(2)));
typedef unsigned char uc8 __attribute__((ext_vector_type(8)));

// ---------------- phist + zero stats/pooled ------------------------------------
__global__ __launch_bounds__(256) void k_encphist(
    const int* __restrict__ ei, float* __restrict__ stats,
    float* __restrict__ pooled, int* __restrict__ pcnt)
{
    __shared__ int hist[256];
    int bb = blockIdx.x, t = threadIdx.x;
    if (bb < NPB) {                                  // ---- phist part
        hist[t] = 0;
        __syncthreads();
        int base4 = bb * (PCHUNK / 4);
        int n4 = min(PCHUNK / 4, N_EDGES / 4 - base4);
        const i32x4* d4 = (const i32x4*)(ei + N_EDGES);
        for (int k = t; k < n4; k += 256) {
            i32x4 d = __builtin_nontemporal_load(d4 + base4 + k);
            atomicAdd(&hist[d.x >> BSHIFT], 1);
            atomicAdd(&hist[d.y >> BSHIFT], 1);
            atomicAdd(&hist[d.z >> BSHIFT], 1);
            atomicAdd(&hist[d.w >> BSHIFT], 1);
        }
        __syncthreads();
        pcnt[t * NPB + bb] = hist[t];
    } else {                                         // ---- zeroing part
        int gid = (bb - NPB) * 256 + t;
        if (gid < NLAYERS * 64)   stats[gid]  = 0.f;
        if (gid < NGRAPHS * HD)   pooled[gid] = 0.f;
    }
}

// per-bucket scan of per-block counts (in place) + bucket totals
__global__ __launch_bounds__(512) void k_pscanA(int* __restrict__ pcnt,
                                                int* __restrict__ btot)
{
    __shared__ int sc[2][512];
    int t = threadIdx.x, b = blockIdx.x;
    int base = b * NPB;
    int v = (t < NPB) ? pcnt[base + t] : 0;
    int pp = 0;
    sc[0][t] = v;
    __syncthreads();
    for (int st = 1; st < 512; st <<= 1) {
        int x = sc[pp][t];
        if (t >= st) x += sc[pp][t - st];
        sc[pp ^ 1][t] = x;
        pp ^= 1;
        __syncthreads();
    }
    int incl = sc[pp][t];
    if (t < NPB) pcnt[base + t] = incl - v;
    if (t == NPB - 1) btot[b] = incl;
}

// scatter packed edges (src<<9 | dstLocal) into dst-bucket regions
__global__ __launch_bounds__(256) void k_pscatter(const int* __restrict__ ei,
                                                  const int* __restrict__ pcnt,
                                                  const int* __restrict__ btot,
                                                  unsigned int* __restrict__ ebuf)
{
    __shared__ int sb[2][256];
    __shared__ int lcur[256];
    int t = threadIdx.x, blk = blockIdx.x;
    sb[0][t] = (t < NBUCK) ? btot[t] : 0;
    __syncthreads();
    int pp = 0;
    for (int st = 1; st < 256; st <<= 1) {
        int v = sb[pp][t];
        if (t >= st) v += sb[pp][t - st];
        sb[pp ^ 1][t] = v;
        pp ^= 1;
        __syncthreads();
    }
    int bexcl = (t == 0) ? 0 : sb[pp][t - 1];
    lcur[t] = pcnt[t * NPB + blk] + bexcl;
    __syncthreads();
    int base4 = blk * (PCHUNK / 4);
    int n4 = min(PCHUNK / 4, N_EDGES / 4 - base4);
    const i32x4* s4 = (const i32x4*)ei;
    const i32x4* d4 = (const i32x4*)(ei + N_EDGES);
    for (int k = t; k < n4; k += 256) {
        i32x4 s = __builtin_nontemporal_load(s4 + base4 + k);
        i32x4 d = __builtin_nontemporal_load(d4 + base4 + k);
        int pos;
        pos = atomicAdd(&lcur[d.x >> BSHIFT], 1);
        ebuf[pos] = ((unsigned)s.x << BSHIFT) | (unsigned)(d.x & 511);
        pos = atomicAdd(&lcur[d.y >> BSHIFT], 1);
        ebuf[pos] = ((unsigned)s.y << BSHIFT) | (unsigned)(d.y & 511);
        pos = atomicAdd(&lcur[d.z >> BSHIFT], 1);
        ebuf[pos] = ((unsigned)s.z << BSHIFT) | (unsigned)(d.z & 511);
        pos = atomicAdd(&lcur[d.w >> BSHIFT], 1);
        ebuf[pos] = ((unsigned)s.w << BSHIFT) | (unsigned)(d.w & 511);
    }
}

// per-bucket local sort -> final CSR + off[] + layer-0 neighbor sums (usum)
__global__ __launch_bounds__(512) void k_bfinal(const unsigned int* __restrict__ ebuf,
                                                const int* __restrict__ btot,
                                                const float* __restrict__ x,
                                                int* __restrict__ off,
                                                int* __restrict__ csr,
                                                float* __restrict__ usum)
{
    __shared__ int sb[2][256];
    __shared__ int cnt[512], scanbuf[2][512], cur[512];
    __shared__ float fsum[512];
    int tid = threadIdx.x, b = blockIdx.x;
    if (tid < 256) sb[0][tid] = (tid < NBUCK) ? btot[tid] : 0;
    fsum[tid] = 0.f;
    __syncthreads();
    int pp = 0;
    for (int st = 1; st < 256; st <<= 1) {
        if (tid < 256) {
            int v = sb[pp][tid];
            if (tid >= st) v += sb[pp][tid - st];
            sb[pp ^ 1][tid] = v;
        }
        pp ^= 1;
        __syncthreads();
    }
    int base = (b == 0) ? 0 : sb[pp][b - 1];
    int nE = sb[pp][b] - base;
    if (b == NBUCK - 1 && tid == 0) off[N_NODES] = sb[pp][NBUCK - 1];
    cnt[tid] = 0;
    __syncthreads();
    for (int e = tid; e < nE; e += 512)
        atomicAdd(&cnt[ebuf[base + e] & 511], 1);
    __syncthreads();
    int p2 = 0;
    scanbuf[0][tid] = cnt[tid];
    __syncthreads();
    for (int st = 1; st < 512; st <<= 1) {
        int v = scanbuf[p2][tid];
        if (tid >= st) v += scanbuf[p2][tid - st];
        scanbuf[p2 ^ 1][tid] = v;
        p2 ^= 1;
        __syncthreads();
    }
    int excl = scanbuf[p2][tid] - cnt[tid];
    cur[tid] = excl;
    int gnode = (b << BSHIFT) + tid;
    if (gnode < N_NODES) off[gnode] = base + excl;
    __syncthreads();
    for (int e = tid; e < nE; e += 512) {
        unsigned int p = ebuf[base + e];
        int src = (int)(p >> BSHIFT);
        int pos = atomicAdd(&cur[p & 511], 1);
        csr[base + pos] = src;
        atomicAdd(&fsum[p & 511], x[src]);           // layer-0 aggregation
    }
    __syncthreads();
    if (gnode < N_NODES) usum[gnode] = fsum[tid];
}

// ---------------- fused GIN layer: agg (+dequant) -> in-wave transpose ->
//                  MFMA MLP -> z2 + BN stats.  One 16-node tile per wave.
// Layer 0 uses precomputed usum (rank-2 identity): z1 = u*W_enc + d*b_enc.
__global__ __launch_bounds__(256, 6) void k_fused(
    const unsigned char* __restrict__ hq, const float* __restrict__ x,
    const float* __restrict__ usum, const int* __restrict__ off,
    const int* __restrict__ csr, const float* __restrict__ epsArr,
    const float* __restrict__ gamma, const float* __restrict__ beta,
    const float* __restrict__ W_enc, const float* __restrict__ b_enc,
    const float* __restrict__ W1, const float* __restrict__ b1,
    const float* __restrict__ W2, const float* __restrict__ b2,
    f16* __restrict__ z2out, float* __restrict__ stats, int layer)
{
    __shared__ f16 AT[4][16][5][8];      // [wave][node][group(pad 4->5)][8ch]
    __shared__ float T[4][16 * 36];
    __shared__ float redS[4][32], redQ[4][32];
    int tid = threadIdx.x, wave = tid >> 6, lane = tid & 63;
    int col = lane & 15, quad = lane >> 4;
    int unit = tid >> 2, li = tid & 3, ul = unit & 15;
    int node = blockIdx.x * 64 + unit;
    bool valid = node < N_NODES;         // wave-uniform: 16 | N_NODES
    int co = li * 8;

    f16x8 r;
    #pragma unroll
    for (int k = 0; k < 8; ++k) r[k] = (f16)0.f;

    if (valid) {
        if (layer == 0) {                // ---- precomputed scalar aggregation
            int j0 = off[node], jend = off[node + 1];
            float oneEps = 1.f + epsArr[0];
            float u  = fmaf(oneEps, x[node], usum[node]);
            float dv = oneEps + (float)(jend - j0);
            #pragma unroll
            for (int k = 0; k < 8; ++k)
                r[k] = (f16)(fmaf(u, W_enc[co + k], dv * b_enc[co + k]));
        } else {                         // ---- int8 gather aggregation
            const unsigned MASK = 0x00FF00FFu;
            int j = off[node], jend = off[node + 1];
            u32x2 gs = *(const u32x2*)(hq + (size_t)node * 32 + co);  // self row
            unsigned a0 = 0, a1 = 0, a2 = 0, a3 = 0;
            auto accum = [&](u32x2 v) {
                a0 += v.x & MASK; a1 += (v.x >> 8) & MASK;
                a2 += v.y & MASK; a3 += (v.y >> 8) & MASK;
            };
            auto rowp = [&](int idx) {
                return (const u32x2*)(hq + (size_t)idx * 32 + co);
            };
            while (j < jend && (j & 3))
                accum(*rowp(csr[j++]));
            int nrem = jend - j;
            while (nrem >= 16) {                     // 16 rows in flight
                i32x4 q0 = __builtin_nontemporal_load((const i32x4*)(csr + j));
                i32x4 q1 = __builtin_nontemporal_load((const i32x4*)(csr + j + 4));
                i32x4 q2 = __builtin_nontemporal_load((const i32x4*)(csr + j + 8));
                i32x4 q3 = __builtin_nontemporal_load((const i32x4*)(csr + j + 12));
                u32x2 g0 = *rowp(q0.x), g1 = *rowp(q0.y);
                u32x2 g2 = *rowp(q0.z), g3 = *rowp(q0.w);
                u32x2 g4 = *rowp(q1.x), g5 = *rowp(q1.y);
                u32x2 g6 = *rowp(q1.z), g7 = *rowp(q1.w);
                u32x2 g8 = *rowp(q2.x), g9 = *rowp(q2.y);
                u32x2 gA = *rowp(q2.z), gB = *rowp(q2.w);
                u32x2 gC = *rowp(q3.x), gD = *rowp(q3.y);
                u32x2 gE = *rowp(q3.z), gF = *rowp(q3.w);
                accum(g0); accum(g1); accum(g2); accum(g3);
                accum(g4); accum(g5); accum(g6); accum(g7);
                accum(g8); accum(g9); accum(gA); accum(gB);
                accum(gC); accum(gD); accum(gE); accum(gF);
                j += 16; nrem -= 16;
            }
            if (nrem >= 8) {
                i32x4 q0 = *(const i32x4*)(csr + j);
                i32x4 q1 = *(const i32x4*)(csr + j + 4);
                u32x2 g0 = *rowp(q0.x), g1 = *rowp(q0.y);
                u32x2 g2 = *rowp(q0.z), g3 = *rowp(q0.w);
                u32x2 g4 = *rowp(q1.x), g5 = *rowp(q1.y);
                u32x2 g6 = *rowp(q1.z), g7 = *rowp(q1.w);
                accum(g0); accum(g1); accum(g2); accum(g3);
                accum(g4); accum(g5); accum(g6); accum(g7);
                j += 8; nrem -= 8;
            }
            if (nrem >= 4) {
                i32x4 q0 = *(const i32x4*)(csr + j);
                accum(*rowp(q0.x)); accum(*rowp(q0.y));
                accum(*rowp(q0.z)); accum(*rowp(q0.w));
                j += 4;
            }
            while (j < jend)
                accum(*rowp(csr[j++]));

            // dequant constants (after the hot loop: fewer live regs in loop)
            float oneEps = 1.f + epsArr[layer];
            float F[8];
            F[0] = (float)(a0 & 0xFFFF); F[2] = (float)(a0 >> 16);
            F[1] = (float)(a1 & 0xFFFF); F[3] = (float)(a1 >> 16);
            F[4] = (float)(a2 & 0xFFFF); F[6] = (float)(a2 >> 16);
            F[5] = (float)(a3 & 0xFFFF); F[7] = (float)(a3 >> 16);
            #pragma unroll
            for (int k = 0; k < 4; ++k) {
                float gLo  = gamma[(layer - 1) * 32 + co + k];
                float bLo  = beta[(layer - 1) * 32 + co + k];
                float gHi  = gamma[(layer - 1) * 32 + co + k + 4];
                float bHi  = beta[(layer - 1) * 32 + co + k + 4];
                float sLo = fmaxf(fmaxf(bLo + 5.5f * fabsf(gLo), 0.f), 1e-6f) / 255.f;
                float sHi = fmaxf(fmaxf(bHi + 5.5f * fabsf(gHi), 0.f), 1e-6f) / 255.f;
                float qsl = (float)((gs.x >> (8 * k)) & 255u);
                float qsh = (float)((gs.y >> (8 * k)) & 255u);
                r[k]     = (f16)(sLo * (F[k]     + oneEps * qsl));
                r[k + 4] = (f16)(sHi * (F[k + 4] + oneEps * qsh));
            }
        }
    }

    // in-wave transpose to MFMA A-fragment layout (wave-synchronous LDS)
    if (valid) *(f16x8*)&AT[wave][ul][li][0] = r;

    float sA = 0.f, qA = 0.f, sB = 0.f, qB = 0.f;
    if (valid) {
        f16x8 a = *(const f16x8*)&AT[wave][col][quad][0];
        const float* W1l = W1 + layer * 1024;
        const float* W2l = W2 + layer * 1024;
        f16x8 w1a, w1b, w2a, w2b;                    // B[k=quad*8+j][n=col(+16)]
        #pragma unroll
        for (int jj = 0; jj < 8; ++jj) {
            int k = quad * 8 + jj;
            w1a[jj] = (f16)W1l[k * 32 + col];
            w1b[jj] = (f16)W1l[k * 32 + col + 16];
            w2a[jj] = (f16)W2l[k * 32 + col];
            w2b[jj] = (f16)W2l[k * 32 + col + 16];
        }
        float b1a = b1[layer * 32 + col], b1b = b1[layer * 32 + col + 16];
        float b2a = b2[layer * 32 + col], b2b = b2[layer * 32 + col + 16];
        f32x4 bias1a = {b1a, b1a, b1a, b1a}, bias1b = {b1b, b1b, b1b, b1b};
        f32x4 bias2a = {b2a, b2a, b2a, b2a}, bias2b = {b2b, b2b, b2b, b2b};
        float* Tw = T[wave];

        f32x4 m0 = __builtin_amdgcn_mfma_f32_16x16x32_f16(a, w1a, bias1a, 0, 0, 0);
        f32x4 m1 = __builtin_amdgcn_mfma_f32_16x16x32_f16(a, w1b, bias1b, 0, 0, 0);
        #pragma unroll
        for (int rr = 0; rr < 4; ++rr) {             // relu + D-layout -> LDS
            int row = quad * 4 + rr;
            Tw[row * 36 + col]      = fmaxf(m0[rr], 0.f);
            Tw[row * 36 + col + 16] = fmaxf(m1[rr], 0.f);
        }
        f32x4 t0 = *(const f32x4*)(Tw + col * 36 + quad * 8);     // wave-sync
        f32x4 t1 = *(const f32x4*)(Tw + col * 36 + quad * 8 + 4);
        f16x8 a2;
        #pragma unroll
        for (int k = 0; k < 4; ++k) { a2[k] = (f16)t0[k]; a2[k + 4] = (f16)t1[k]; }
        f32x4 z0 = __builtin_amdgcn_mfma_f32_16x16x32_f16(a2, w2a, bias2a, 0, 0, 0);
        f32x4 zb = __builtin_amdgcn_mfma_f32_16x16x32_f16(a2, w2b, bias2b, 0, 0, 0);
        int nb = blockIdx.x * 64 + wave * 16;
        #pragma unroll
        for (int rr = 0; rr < 4; ++rr) {
            int n2 = nb + quad * 4 + rr;
            __builtin_nontemporal_store((f16)z0[rr], z2out + n2 * 32 + col);
            __builtin_nontemporal_store((f16)zb[rr], z2out + n2 * 32 + col + 16);
            sA += z0[rr]; qA += z0[rr] * z0[rr];
            sB += zb[rr]; qB += zb[rr] * zb[rr];
        }
    }

    sA += __shfl_xor(sA, 16); sA += __shfl_xor(sA, 32);
    qA += __shfl_xor(qA, 16); qA += __shfl_xor(qA, 32);
    sB += __shfl_xor(sB, 16); sB += __shfl_xor(sB, 32);
    qB += __shfl_xor(qB, 16); qB += __shfl_xor(qB, 32);
    if (lane < 16) {
        redS[wave][col] = sA; redS[wave][col + 16] = sB;
        redQ[wave][col] = qA; redQ[wave][col + 16] = qB;
    }
    __syncthreads();
    if (tid < 64) {
        int sel = tid >> 5, cc = tid & 31;
        float s = 0.f;
        #pragma unroll
        for (int w = 0; w < 4; ++w) s += sel ? redQ[w][cc] : redS[w][cc];
        atomicAdd(&stats[layer * 64 + sel * 32 + cc], s);
    }
}

// ---------------- quantize: hq = uint8( relu(BN(z2)) / s )  -------------------
__global__ __launch_bounds__(256) void k_quant(
    const f16* __restrict__ z2, const float* __restrict__ stats,
    const float* __restrict__ gamma, const float* __restrict__ beta,
    unsigned char* __restrict__ hq, int layer)
{
    int idx = blockIdx.x * 256 + threadIdx.x;        // over N*4 (8 ch each)
    if (idx >= N_NODES * 4) return;
    int c0 = (idx & 3) * 8;
    const float invN = 1.0f / (float)N_NODES;
    float bnsc[8], bnsh[8], inv_s[8];
    #pragma unroll
    for (int k = 0; k < 8; ++k) {
        int ch = c0 + k;
        float g = gamma[layer * 32 + ch], bb = beta[layer * 32 + ch];
        float mu  = stats[layer * 64 + ch] * invN;
        float var = stats[layer * 64 + 32 + ch] * invN - mu * mu;
        float sc = g * rsqrtf(var + BN_EPS);
        bnsc[k] = sc;
        bnsh[k] = bb - mu * sc;
        float vmax = fmaxf(bb + 5.5f * fabsf(g), 0.f);
        inv_s[k] = 255.f / fmaxf(vmax, 1e-6f);       // matches k_fused dq_s
    }
    f16x8 z = *(const f16x8*)(z2 + (size_t)idx * 8);
    uc8 r;
    #pragma unroll
    for (int k = 0; k < 8; ++k) {
        float v = fmaxf(fmaf((float)z[k], bnsc[k], bnsh[k]), 0.f);
        int q = (int)(fminf(v * inv_s[k], 255.f) + 0.5f);
        r[k] = (unsigned char)q;
    }
    __builtin_nontemporal_store(r, (uc8*)(hq + (size_t)idx * 8));
}

// ---------------- global_add_pool with inline BN(3)+ReLU -----------------------
__global__ __launch_bounds__(256) void k_pool(const f16* __restrict__ z2,
                                              const int* __restrict__ batch,
                                              const float* __restrict__ stats,
                                              const float* __restrict__ gamma,
                                              const float* __restrict__ beta,
                                              float* __restrict__ pooled)
{
    int c = threadIdx.x & 31, slot = threadIdx.x >> 5;
    const float invN = 1.0f / (float)N_NODES;
    float mu  = stats[3 * 64 + c] * invN;
    float var = stats[3 * 64 + 32 + c] * invN - mu * mu;
    float sc = gamma[3 * 32 + c] * rsqrtf(var + BN_EPS);
    float sh = beta[3 * 32 + c] - mu * sc;
    int start = blockIdx.x * 256 + slot * 32;
    if (start >= N_NODES) return;
    int end = min(start + 32, N_NODES);
    int cur = batch[start]; float acc = 0.f;
    for (int i = start; i < end; ++i) {
        int g = batch[i];
        if (g != cur) { atomicAdd(&pooled[cur * HD + c], acc); acc = 0.f; cur = g; }
        acc += fmaxf(fmaf((float)z2[i * 32 + c], sc, sh), 0.f);
    }
    atomicAdd(&pooled[cur * HD + c], acc);
}

// ---------------- classifier ---------------------------------------------------
__global__ __launch_bounds__(256) void k_cls(const float* __restrict__ pooled,
                                             const float* __restrict__ Wc,
                                             const float* __restrict__ bc,
                                             float* __restrict__ out)
{
    int gid = blockIdx.x * 256 + threadIdx.x;
    if (gid >= NGRAPHS * 2) return;
    int g = gid >> 1, c = gid & 1;
    float s = bc[c];
    #pragma unroll
    for (int k = 0; k < 32; ++k) s = fmaf(pooled[g * 32 + k], Wc[k * 2 + c], s);
    out[gid] = s;
}

extern "C" void kernel_launch(void* const* d_in, const int* in_sizes, int n_in,
                              void* d_out, int out_size, void* d_ws, size_t ws_size,
                              hipStream_t stream)
{
    const float* x      = (const float*)d_in[0];
    const int*   ei     = (const int*)d_in[1];
    const int*   batch  = (const int*)d_in[2];
    const float* W_enc  = (const float*)d_in[3];
    const float* b_enc  = (const float*)d_in[4];
    const float* epsArr = (const float*)d_in[5];
    const float* W1     = (const float*)d_in[6];
    const float* b1     = (const float*)d_in[7];
    const float* W2     = (const float*)d_in[8];
    const float* b2     = (const float*)d_in[9];
    const float* gamma  = (const float*)d_in[10];
    const float* beta   = (const float*)d_in[11];
    const float* Wc     = (const float*)d_in[12];
    const float* bc     = (const float*)d_in[13];
    float* out = (float*)d_out;

    char* ws = (char*)d_ws;
    size_t o = 0;
    auto alloc = [&](size_t bytes) {
        char* p = ws + o;
        o += (bytes + 255) & ~(size_t)255;
        return p;
    };
    unsigned char* hq = (unsigned char*)alloc((size_t)N_NODES * 32);  // 3.2 MB
    f16*   z2     = (f16*) alloc((size_t)N_NODES * 32 * 2);    // 6.4 MB [node][32]
    int*   csr    = (int*) alloc((size_t)N_EDGES * 4);         // 12.8 MB
    unsigned int* ebuf = (unsigned int*)alloc((size_t)N_EDGES * 4);  // 12.8 MB
    int*   offA   = (int*) alloc((size_t)(N_NODES + 1) * 4);
    float* usum   = (float*)alloc((size_t)N_NODES * 4);        // 0.4 MB
    int*   pcnt   = (int*) alloc((size_t)256 * NPB * 4);       // 0.4 MB
    int*   btot   = (int*) alloc(1024);
    float* stats  = (float*)alloc(NLAYERS * 64 * 4);
    float* pooled = (float*)alloc((size_t)NGRAPHS * HD * 4);

    k_encphist<<<NPB + ZBLOCKS, 256, 0, stream>>>(ei, stats, pooled, pcnt);
    k_pscanA  <<<NBUCK, 512, 0, stream>>>(pcnt, btot);
    k_pscatter<<<NPB, 256, 0, stream>>>(ei, pcnt, btot, ebuf);
    k_bfinal  <<<NBUCK, 512, 0, stream>>>(ebuf, btot, x, offA, csr, usum);

    for (int l = 0; l < NLAYERS; ++l) {
        k_fused<<<(N_NODES + 63) / 64, 256, 0, stream>>>(
            hq, x, usum, offA, csr, epsArr, gamma, beta, W_enc, b_enc,
            W1, b1, W2, b2, z2, stats, l);
        if (l < NLAYERS - 1)
            k_quant<<<(N_NODES * 4 + 255) / 256, 256, 0, stream>>>(z2, stats,
                                                                   gamma, beta,
                                                                   hq, l);
    }
    k_pool<<<(N_NODES + 255) / 256, 256, 0, stream>>>(z2, batch, stats,
                                                      gamma, beta, pooled);
    k_cls <<<8, 256, 0, stream>>>(pooled, Wc, bc, out);
}

// Round 3
// 419.143 us; speedup vs baseline: 1.0575x; 1.0575x over previous
//
#include <hip/hip_runtime.h>

#define N_NODES 100000
#define N_EDGES 3200000
#define HD      32
#define NLAYERS 4
#define NGRAPHS 1000
#define BN_EPS  1e-5f
#define BSHIFT  9                         // 512-node buckets
#define NBUCK   ((N_NODES + 511) >> 9)    // 196
#define PCHUNK  8192                      // edges per partition block
#define NPB     ((N_EDGES + PCHUNK - 1) / PCHUNK)   // 391
#define ZBLOCKS ((NGRAPHS * HD + 255) / 256)        // 125

typedef _Float16 f16;
typedef _Float16 f16x4 __attribute__((ext_vector_type(4)));
typedef _Float16 f16x8 __attribute__((ext_vector_type(8)));
typedef float    f32x4 __attribute__((ext_vector_type(4)));
typedef int      i32x4 __attribute__((ext_vector_type(4)));
typedef unsigned int  u32x2 __attribute__((ext_vector_type(2)));
typedef unsigned char uc8 __attribute__((ext_vector_type(8)));

// ---------------- phist + zero stats/pooled ------------------------------------
__global__ __launch_bounds__(256) void k_encphist(
    const int* __restrict__ ei, float* __restrict__ stats,
    float* __restrict__ pooled, int* __restrict__ pcnt)
{
    __shared__ int hist[256];
    int bb = blockIdx.x, t = threadIdx.x;
    if (bb < NPB) {                                  // ---- phist part
        hist[t] = 0;
        __syncthreads();
        int base4 = bb * (PCHUNK / 4);
        int n4 = min(PCHUNK / 4, N_EDGES / 4 - base4);
        const i32x4* d4 = (const i32x4*)(ei + N_EDGES);
        for (int k = t; k < n4; k += 256) {
            i32x4 d = __builtin_nontemporal_load(d4 + base4 + k);
            atomicAdd(&hist[d.x >> BSHIFT], 1);
            atomicAdd(&hist[d.y >> BSHIFT], 1);
            atomicAdd(&hist[d.z >> BSHIFT], 1);
            atomicAdd(&hist[d.w >> BSHIFT], 1);
        }
        __syncthreads();
        pcnt[t * NPB + bb] = hist[t];
    } else {                                         // ---- zeroing part
        int gid = (bb - NPB) * 256 + t;
        if (gid < NLAYERS * 64)   stats[gid]  = 0.f;
        if (gid < NGRAPHS * HD)   pooled[gid] = 0.f;
    }
}

// per-bucket scan of per-block counts (in place) + bucket totals
__global__ __launch_bounds__(512) void k_pscanA(int* __restrict__ pcnt,
                                                int* __restrict__ btot)
{
    __shared__ int sc[2][512];
    int t = threadIdx.x, b = blockIdx.x;
    int base = b * NPB;
    int v = (t < NPB) ? pcnt[base + t] : 0;
    int pp = 0;
    sc[0][t] = v;
    __syncthreads();
    for (int st = 1; st < 512; st <<= 1) {
        int x = sc[pp][t];
        if (t >= st) x += sc[pp][t - st];
        sc[pp ^ 1][t] = x;
        pp ^= 1;
        __syncthreads();
    }
    int incl = sc[pp][t];
    if (t < NPB) pcnt[base + t] = incl - v;
    if (t == NPB - 1) btot[b] = incl;
}

// scatter packed edges (src<<9 | dstLocal) into dst-bucket regions
__global__ __launch_bounds__(256) void k_pscatter(const int* __restrict__ ei,
                                                  const int* __restrict__ pcnt,
                                                  const int* __restrict__ btot,
                                                  unsigned int* __restrict__ ebuf)
{
    __shared__ int sb[2][256];
    __shared__ int lcur[256];
    int t = threadIdx.x, blk = blockIdx.x;
    sb[0][t] = (t < NBUCK) ? btot[t] : 0;
    __syncthreads();
    int pp = 0;
    for (int st = 1; st < 256; st <<= 1) {
        int v = sb[pp][t];
        if (t >= st) v += sb[pp][t - st];
        sb[pp ^ 1][t] = v;
        pp ^= 1;
        __syncthreads();
    }
    int bexcl = (t == 0) ? 0 : sb[pp][t - 1];
    lcur[t] = pcnt[t * NPB + blk] + bexcl;
    __syncthreads();
    int base4 = blk * (PCHUNK / 4);
    int n4 = min(PCHUNK / 4, N_EDGES / 4 - base4);
    const i32x4* s4 = (const i32x4*)ei;
    const i32x4* d4 = (const i32x4*)(ei + N_EDGES);
    for (int k = t; k < n4; k += 256) {
        i32x4 s = __builtin_nontemporal_load(s4 + base4 + k);
        i32x4 d = __builtin_nontemporal_load(d4 + base4 + k);
        int pos;
        pos = atomicAdd(&lcur[d.x >> BSHIFT], 1);
        ebuf[pos] = ((unsigned)s.x << BSHIFT) | (unsigned)(d.x & 511);
        pos = atomicAdd(&lcur[d.y >> BSHIFT], 1);
        ebuf[pos] = ((unsigned)s.y << BSHIFT) | (unsigned)(d.y & 511);
        pos = atomicAdd(&lcur[d.z >> BSHIFT], 1);
        ebuf[pos] = ((unsigned)s.z << BSHIFT) | (unsigned)(d.z & 511);
        pos = atomicAdd(&lcur[d.w >> BSHIFT], 1);
        ebuf[pos] = ((unsigned)s.w << BSHIFT) | (unsigned)(d.w & 511);
    }
}

// per-bucket local sort -> final CSR + off[] + layer-0 neighbor sums (usum)
__global__ __launch_bounds__(512) void k_bfinal(const unsigned int* __restrict__ ebuf,
                                                const int* __restrict__ btot,
                                                const float* __restrict__ x,
                                                int* __restrict__ off,
                                                int* __restrict__ csr,
                                                float* __restrict__ usum)
{
    __shared__ int sb[2][256];
    __shared__ int cnt[512], scanbuf[2][512], cur[512];
    __shared__ float fsum[512];
    int tid = threadIdx.x, b = blockIdx.x;
    if (tid < 256) sb[0][tid] = (tid < NBUCK) ? btot[tid] : 0;
    fsum[tid] = 0.f;
    __syncthreads();
    int pp = 0;
    for (int st = 1; st < 256; st <<= 1) {
        if (tid < 256) {
            int v = sb[pp][tid];
            if (tid >= st) v += sb[pp][tid - st];
            sb[pp ^ 1][tid] = v;
        }
        pp ^= 1;
        __syncthreads();
    }
    int base = (b == 0) ? 0 : sb[pp][b - 1];
    int nE = sb[pp][b] - base;
    if (b == NBUCK - 1 && tid == 0) off[N_NODES] = sb[pp][NBUCK - 1];
    cnt[tid] = 0;
    __syncthreads();
    for (int e = tid; e < nE; e += 512)
        atomicAdd(&cnt[ebuf[base + e] & 511], 1);
    __syncthreads();
    int p2 = 0;
    scanbuf[0][tid] = cnt[tid];
    __syncthreads();
    for (int st = 1; st < 512; st <<= 1) {
        int v = scanbuf[p2][tid];
        if (tid >= st) v += scanbuf[p2][tid - st];
        scanbuf[p2 ^ 1][tid] = v;
        p2 ^= 1;
        __syncthreads();
    }
    int excl = scanbuf[p2][tid] - cnt[tid];
    cur[tid] = excl;
    int gnode = (b << BSHIFT) + tid;
    if (gnode < N_NODES) off[gnode] = base + excl;
    __syncthreads();
    for (int e = tid; e < nE; e += 512) {
        unsigned int p = ebuf[base + e];
        int src = (int)(p >> BSHIFT);
        int pos = atomicAdd(&cur[p & 511], 1);
        csr[base + pos] = src;
        atomicAdd(&fsum[p & 511], x[src]);           // layer-0 aggregation
    }
    __syncthreads();
    if (gnode < N_NODES) usum[gnode] = fsum[tid];
}

// ---------------- fused GIN layer: deep-pipelined gather -> LDS transpose ->
//                  MFMA MLP -> z2 + BN stats.  512 thr / 64 nodes / block.
// Gather: 8 lanes per node, 4B per lane per edge (1 line/edge), 16 loads in
// flight, csr lane-loaded + shfl-broadcast, next-batch csr prefetched before
// the accumulate drain.  Layer 0 uses precomputed usum (rank-2 identity).
__global__ __launch_bounds__(512, 8) void k_fused(
    const unsigned char* __restrict__ hq, const float* __restrict__ x,
    const float* __restrict__ usum, const int* __restrict__ off,
    const int* __restrict__ csr, const float* __restrict__ epsArr,
    const float* __restrict__ gamma, const float* __restrict__ beta,
    const float* __restrict__ W_enc, const float* __restrict__ b_enc,
    const float* __restrict__ W1, const float* __restrict__ b1,
    const float* __restrict__ W2, const float* __restrict__ b2,
    f16* __restrict__ z2out, float* __restrict__ stats, int layer)
{
    __shared__ f16 AT[64][40];           // stride 40: 16B-aligned, ~2-way banks
    __shared__ float T[4][16 * 36];
    __shared__ float redS[4][32], redQ[4][32];
    int tid = threadIdx.x, wave = tid >> 6, lane = tid & 63;
    int unit = tid >> 3, li = tid & 7;   // 64 nodes/block, 8 lanes/node
    int lbase = lane & 56;               // unit's lane-0 within wave
    int node = blockIdx.x * 64 + unit;
    int c0 = li * 4;                     // this lane's 4 channels

    if (node < N_NODES) {
        f16x4 r;
        if (layer == 0) {                // ---- precomputed scalar aggregation
            float oneEps = 1.f + epsArr[0];
            float u  = fmaf(oneEps, x[node], usum[node]);
            float dv = oneEps + (float)(off[node + 1] - off[node]);
            #pragma unroll
            for (int k = 0; k < 4; ++k)
                r[k] = (f16)(fmaf(u, W_enc[c0 + k], dv * b_enc[c0 + k]));
        } else {                         // ---- int8 gather, deep-pipelined
            const unsigned MASK = 0x00FF00FFu;
            const unsigned char* hql = hq + c0;
            int j = off[node], jend = off[node + 1];
            int navail = jend - j;
            unsigned qv = *(const unsigned*)(hql + (size_t)node * 32); // self
            int ci0 = 0, ci1 = 0;
            if (li < navail)     ci0 = __builtin_nontemporal_load(csr + j + li);
            if (8 + li < navail) ci1 = __builtin_nontemporal_load(csr + j + 8 + li);
            unsigned a0 = 0, a1 = 0;
            while (navail >= 16) {
                unsigned g[16];
                #pragma unroll
                for (int e = 0; e < 8; ++e) {
                    int i0 = __shfl(ci0, lbase | e);
                    int i1 = __shfl(ci1, lbase | e);
                    g[e]     = *(const unsigned*)(hql + (size_t)i0 * 32);
                    g[e + 8] = *(const unsigned*)(hql + (size_t)i1 * 32);
                }
                j += 16; navail -= 16;   // prefetch next csr before the drain
                if (li < navail)     ci0 = __builtin_nontemporal_load(csr + j + li);
                if (8 + li < navail) ci1 = __builtin_nontemporal_load(csr + j + 8 + li);
                #pragma unroll
                for (int e = 0; e < 16; ++e) {
                    a0 += g[e] & MASK; a1 += (g[e] >> 8) & MASK;
                }
            }
            if (navail >= 8) {
                unsigned g[8];
                #pragma unroll
                for (int e = 0; e < 8; ++e) {
                    int i0 = __shfl(ci0, lbase | e);
                    g[e] = *(const unsigned*)(hql + (size_t)i0 * 32);
                }
                ci0 = ci1; j += 8; navail -= 8;
                #pragma unroll
                for (int e = 0; e < 8; ++e) {
                    a0 += g[e] & MASK; a1 += (g[e] >> 8) & MASK;
                }
            }
            for (int e = 0; e < navail; ++e) {
                int i0 = __shfl(ci0, lbase | e);
                unsigned g = *(const unsigned*)(hql + (size_t)i0 * 32);
                a0 += g & MASK; a1 += (g >> 8) & MASK;
            }
            // dequant: channels c0..c0+3
            float oneEps = 1.f + epsArr[layer];
            float F[4];
            F[0] = (float)(a0 & 0xFFFF); F[2] = (float)(a0 >> 16);
            F[1] = (float)(a1 & 0xFFFF); F[3] = (float)(a1 >> 16);
            #pragma unroll
            for (int k = 0; k < 4; ++k) {
                float g  = gamma[(layer - 1) * 32 + c0 + k];
                float bb = beta[(layer - 1) * 32 + c0 + k];
                float s  = fmaxf(fmaxf(bb + 5.5f * fabsf(g), 0.f), 1e-6f) / 255.f;
                float q  = (float)((qv >> (8 * k)) & 255u);
                r[k] = (f16)(s * (F[k] + oneEps * q));
            }
        }
        *(f16x4*)&AT[unit][c0] = r;      // LDS transpose write
    }
    __syncthreads();

    // ---- MFMA MLP: waves 0-3, one 16-node tile each ----
    int col = lane & 15, quad = lane >> 4;
    float sA = 0.f, qA = 0.f, sB = 0.f, qB = 0.f;
    int nb = blockIdx.x * 64 + wave * 16;
    if (wave < 4 && nb < N_NODES) {
        f16x8 a = *(const f16x8*)&AT[wave * 16 + col][quad * 8];
        const float* W1l = W1 + layer * 1024;
        const float* W2l = W2 + layer * 1024;
        f16x8 w1a, w1b, w2a, w2b;                    // B[k=quad*8+j][n=col(+16)]
        #pragma unroll
        for (int jj = 0; jj < 8; ++jj) {
            int k = quad * 8 + jj;
            w1a[jj] = (f16)W1l[k * 32 + col];
            w1b[jj] = (f16)W1l[k * 32 + col + 16];
            w2a[jj] = (f16)W2l[k * 32 + col];
            w2b[jj] = (f16)W2l[k * 32 + col + 16];
        }
        float b1a = b1[layer * 32 + col], b1b = b1[layer * 32 + col + 16];
        float b2a = b2[layer * 32 + col], b2b = b2[layer * 32 + col + 16];
        f32x4 bias1a = {b1a, b1a, b1a, b1a}, bias1b = {b1b, b1b, b1b, b1b};
        f32x4 bias2a = {b2a, b2a, b2a, b2a}, bias2b = {b2b, b2b, b2b, b2b};
        float* Tw = T[wave];

        f32x4 m0 = __builtin_amdgcn_mfma_f32_16x16x32_f16(a, w1a, bias1a, 0, 0, 0);
        f32x4 m1 = __builtin_amdgcn_mfma_f32_16x16x32_f16(a, w1b, bias1b, 0, 0, 0);
        #pragma unroll
        for (int rr = 0; rr < 4; ++rr) {             // relu + D-layout -> LDS
            int row = quad * 4 + rr;
            Tw[row * 36 + col]      = fmaxf(m0[rr], 0.f);
            Tw[row * 36 + col + 16] = fmaxf(m1[rr], 0.f);
        }
        f32x4 t0 = *(const f32x4*)(Tw + col * 36 + quad * 8);     // wave-sync
        f32x4 t1 = *(const f32x4*)(Tw + col * 36 + quad * 8 + 4);
        f16x8 a2;
        #pragma unroll
        for (int k = 0; k < 4; ++k) { a2[k] = (f16)t0[k]; a2[k + 4] = (f16)t1[k]; }
        f32x4 z0 = __builtin_amdgcn_mfma_f32_16x16x32_f16(a2, w2a, bias2a, 0, 0, 0);
        f32x4 zb = __builtin_amdgcn_mfma_f32_16x16x32_f16(a2, w2b, bias2b, 0, 0, 0);
        #pragma unroll
        for (int rr = 0; rr < 4; ++rr) {
            int n2 = nb + quad * 4 + rr;
            __builtin_nontemporal_store((f16)z0[rr], z2out + n2 * 32 + col);
            __builtin_nontemporal_store((f16)zb[rr], z2out + n2 * 32 + col + 16);
            sA += z0[rr]; qA += z0[rr] * z0[rr];
            sB += zb[rr]; qB += zb[rr] * zb[rr];
        }
    }
    if (wave < 4) {
        sA += __shfl_xor(sA, 16); sA += __shfl_xor(sA, 32);
        qA += __shfl_xor(qA, 16); qA += __shfl_xor(qA, 32);
        sB += __shfl_xor(sB, 16); sB += __shfl_xor(sB, 32);
        qB += __shfl_xor(qB, 16); qB += __shfl_xor(qB, 32);
        if (lane < 16) {
            redS[wave][col] = sA; redS[wave][col + 16] = sB;
            redQ[wave][col] = qA; redQ[wave][col + 16] = qB;
        }
    }
    __syncthreads();
    if (tid < 64) {
        int sel = tid >> 5, cc = tid & 31;
        float s = 0.f;
        #pragma unroll
        for (int w = 0; w < 4; ++w) s += sel ? redQ[w][cc] : redS[w][cc];
        atomicAdd(&stats[layer * 64 + sel * 32 + cc], s);
    }
}

// ---------------- quantize: hq = uint8( relu(BN(z2)) / s )  -------------------
__global__ __launch_bounds__(256) void k_quant(
    const f16* __restrict__ z2, const float* __restrict__ stats,
    const float* __restrict__ gamma, const float* __restrict__ beta,
    unsigned char* __restrict__ hq, int layer)
{
    int idx = blockIdx.x * 256 + threadIdx.x;        // over N*4 (8 ch each)
    if (idx >= N_NODES * 4) return;
    int c0 = (idx & 3) * 8;
    const float invN = 1.0f / (float)N_NODES;
    float bnsc[8], bnsh[8], inv_s[8];
    #pragma unroll
    for (int k = 0; k < 8; ++k) {
        int ch = c0 + k;
        float g = gamma[layer * 32 + ch], bb = beta[layer * 32 + ch];
        float mu  = stats[layer * 64 + ch] * invN;
        float var = stats[layer * 64 + 32 + ch] * invN - mu * mu;
        float sc = g * rsqrtf(var + BN_EPS);
        bnsc[k] = sc;
        bnsh[k] = bb - mu * sc;
        float vmax = fmaxf(bb + 5.5f * fabsf(g), 0.f);
        inv_s[k] = 255.f / fmaxf(vmax, 1e-6f);       // matches k_fused dq_s
    }
    f16x8 z = *(const f16x8*)(z2 + (size_t)idx * 8);
    uc8 r;
    #pragma unroll
    for (int k = 0; k < 8; ++k) {
        float v = fmaxf(fmaf((float)z[k], bnsc[k], bnsh[k]), 0.f);
        int q = (int)(fminf(v * inv_s[k], 255.f) + 0.5f);
        r[k] = (unsigned char)q;
    }
    __builtin_nontemporal_store(r, (uc8*)(hq + (size_t)idx * 8));
}

// ---------------- global_add_pool with inline BN(3)+ReLU -----------------------
__global__ __launch_bounds__(256) void k_pool(const f16* __restrict__ z2,
                                              const int* __restrict__ batch,
                                              const float* __restrict__ stats,
                                              const float* __restrict__ gamma,
                                              const float* __restrict__ beta,
                                              float* __restrict__ pooled)
{
    int c = threadIdx.x & 31, slot = threadIdx.x >> 5;
    const float invN = 1.0f / (float)N_NODES;
    float mu  = stats[3 * 64 + c] * invN;
    float var = stats[3 * 64 + 32 + c] * invN - mu * mu;
    float sc = gamma[3 * 32 + c] * rsqrtf(var + BN_EPS);
    float sh = beta[3 * 32 + c] - mu * sc;
    int start = blockIdx.x * 256 + slot * 32;
    if (start >= N_NODES) return;
    int end = min(start + 32, N_NODES);
    int cur = batch[start]; float acc = 0.f;
    for (int i = start; i < end; ++i) {
        int g = batch[i];
        if (g != cur) { atomicAdd(&pooled[cur * HD + c], acc); acc = 0.f; cur = g; }
        acc += fmaxf(fmaf((float)z2[i * 32 + c], sc, sh), 0.f);
    }
    atomicAdd(&pooled[cur * HD + c], acc);
}

// ---------------- classifier ---------------------------------------------------
__global__ __launch_bounds__(256) void k_cls(const float* __restrict__ pooled,
                                             const float* __restrict__ Wc,
                                             const float* __restrict__ bc,
                                             float* __restrict__ out)
{
    int gid = blockIdx.x * 256 + threadIdx.x;
    if (gid >= NGRAPHS * 2) return;
    int g = gid >> 1, c = gid & 1;
    float s = bc[c];
    #pragma unroll
    for (int k = 0; k < 32; ++k) s = fmaf(pooled[g * 32 + k], Wc[k * 2 + c], s);
    out[gid] = s;
}

extern "C" void kernel_launch(void* const* d_in, const int* in_sizes, int n_in,
                              void* d_out, int out_size, void* d_ws, size_t ws_size,
                              hipStream_t stream)
{
    const float* x      = (const float*)d_in[0];
    const int*   ei     = (const int*)d_in[1];
    const int*   batch  = (const int*)d_in[2];
    const float* W_enc  = (const float*)d_in[3];
    const float* b_enc  = (const float*)d_in[4];
    const float* epsArr = (const float*)d_in[5];
    const float* W1     = (const float*)d_in[6];
    const float* b1     = (const float*)d_in[7];
    const float* W2     = (const float*)d_in[8];
    const float* b2     = (const float*)d_in[9];
    const float* gamma  = (const float*)d_in[10];
    const float* beta   = (const float*)d_in[11];
    const float* Wc     = (const float*)d_in[12];
    const float* bc     = (const float*)d_in[13];
    float* out = (float*)d_out;

    char* ws = (char*)d_ws;
    size_t o = 0;
    auto alloc = [&](size_t bytes) {
        char* p = ws + o;
        o += (bytes + 255) & ~(size_t)255;
        return p;
    };
    unsigned char* hq = (unsigned char*)alloc((size_t)N_NODES * 32);  // 3.2 MB
    f16*   z2     = (f16*) alloc((size_t)N_NODES * 32 * 2);    // 6.4 MB [node][32]
    int*   csr    = (int*) alloc((size_t)N_EDGES * 4);         // 12.8 MB
    unsigned int* ebuf = (unsigned int*)alloc((size_t)N_EDGES * 4);  // 12.8 MB
    int*   offA   = (int*) alloc((size_t)(N_NODES + 1) * 4);
    float* usum   = (float*)alloc((size_t)N_NODES * 4);        // 0.4 MB
    int*   pcnt   = (int*) alloc((size_t)256 * NPB * 4);       // 0.4 MB
    int*   btot   = (int*) alloc(1024);
    float* stats  = (float*)alloc(NLAYERS * 64 * 4);
    float* pooled = (float*)alloc((size_t)NGRAPHS * HD * 4);

    k_encphist<<<NPB + ZBLOCKS, 256, 0, stream>>>(ei, stats, pooled, pcnt);
    k_pscanA  <<<NBUCK, 512, 0, stream>>>(pcnt, btot);
    k_pscatter<<<NPB, 256, 0, stream>>>(ei, pcnt, btot, ebuf);
    k_bfinal  <<<NBUCK, 512, 0, stream>>>(ebuf, btot, x, offA, csr, usum);

    for (int l = 0; l < NLAYERS; ++l) {
        k_fused<<<(N_NODES + 63) / 64, 512, 0, stream>>>(
            hq, x, usum, offA, csr, epsArr, gamma, beta, W_enc, b_enc,
            W1, b1, W2, b2, z2, stats, l);
        if (l < NLAYERS - 1)
            k_quant<<<(N_NODES * 4 + 255) / 256, 256, 0, stream>>>(z2, stats,
                                                                   gamma, beta,
                                                                   hq, l);
    }
    k_pool<<<(N_NODES + 255) / 256, 256, 0, stream>>>(z2, batch, stats,
                                                      gamma, beta, pooled);
    k_cls <<<8, 256, 0, stream>>>(pooled, Wc, bc, out);
}

// Round 4
// 416.556 us; speedup vs baseline: 1.0640x; 1.0062x over previous
//
#include <hip/hip_runtime.h>

#define N_NODES 100000
#define N_EDGES 3200000
#define HD      32
#define NLAYERS 4
#define NGRAPHS 1000
#define BN_EPS  1e-5f
#define BSHIFT  9                         // 512-node buckets
#define NBUCK   ((N_NODES + 511) >> 9)    // 196
#define PCHUNK  8192                      // edges per partition block
#define NPB     ((N_EDGES + PCHUNK - 1) / PCHUNK)   // 391
#define ZBLOCKS ((NGRAPHS * HD + 255) / 256)        // 125

typedef _Float16 f16;
typedef _Float16 f16x4 __attribute__((ext_vector_type(4)));
typedef _Float16 f16x8 __attribute__((ext_vector_type(8)));
typedef float    f32x4 __attribute__((ext_vector_type(4)));
typedef int      i32x4 __attribute__((ext_vector_type(4)));
typedef unsigned int  u32x2 __attribute__((ext_vector_type(2)));
typedef unsigned char uc8 __attribute__((ext_vector_type(8)));

// L2-direct load (bypasses vector L1 / its miss queue): agent-scope relaxed.
__device__ __forceinline__ unsigned ld_l2_u32(const void* p) {
    return __hip_atomic_load((const unsigned*)p, __ATOMIC_RELAXED,
                             __HIP_MEMORY_SCOPE_AGENT);
}

// ---------------- phist + zero stats/pooled ------------------------------------
__global__ __launch_bounds__(256) void k_encphist(
    const int* __restrict__ ei, float* __restrict__ stats,
    float* __restrict__ pooled, int* __restrict__ pcnt)
{
    __shared__ int hist[256];
    int bb = blockIdx.x, t = threadIdx.x;
    if (bb < NPB) {                                  // ---- phist part
        hist[t] = 0;
        __syncthreads();
        int base4 = bb * (PCHUNK / 4);
        int n4 = min(PCHUNK / 4, N_EDGES / 4 - base4);
        const i32x4* d4 = (const i32x4*)(ei + N_EDGES);
        for (int k = t; k < n4; k += 256) {
            i32x4 d = __builtin_nontemporal_load(d4 + base4 + k);
            atomicAdd(&hist[d.x >> BSHIFT], 1);
            atomicAdd(&hist[d.y >> BSHIFT], 1);
            atomicAdd(&hist[d.z >> BSHIFT], 1);
            atomicAdd(&hist[d.w >> BSHIFT], 1);
        }
        __syncthreads();
        pcnt[t * NPB + bb] = hist[t];
    } else {                                         // ---- zeroing part
        int gid = (bb - NPB) * 256 + t;
        if (gid < NLAYERS * 64)   stats[gid]  = 0.f;
        if (gid < NGRAPHS * HD)   pooled[gid] = 0.f;
    }
}

// per-bucket scan of per-block counts (in place) + bucket totals
__global__ __launch_bounds__(512) void k_pscanA(int* __restrict__ pcnt,
                                                int* __restrict__ btot)
{
    __shared__ int sc[2][512];
    int t = threadIdx.x, b = blockIdx.x;
    int base = b * NPB;
    int v = (t < NPB) ? pcnt[base + t] : 0;
    int pp = 0;
    sc[0][t] = v;
    __syncthreads();
    for (int st = 1; st < 512; st <<= 1) {
        int x = sc[pp][t];
        if (t >= st) x += sc[pp][t - st];
        sc[pp ^ 1][t] = x;
        pp ^= 1;
        __syncthreads();
    }
    int incl = sc[pp][t];
    if (t < NPB) pcnt[base + t] = incl - v;
    if (t == NPB - 1) btot[b] = incl;
}

// scatter packed edges (src<<9 | dstLocal) into dst-bucket regions
__global__ __launch_bounds__(256) void k_pscatter(const int* __restrict__ ei,
                                                  const int* __restrict__ pcnt,
                                                  const int* __restrict__ btot,
                                                  unsigned int* __restrict__ ebuf)
{
    __shared__ int sb[2][256];
    __shared__ int lcur[256];
    int t = threadIdx.x, blk = blockIdx.x;
    sb[0][t] = (t < NBUCK) ? btot[t] : 0;
    __syncthreads();
    int pp = 0;
    for (int st = 1; st < 256; st <<= 1) {
        int v = sb[pp][t];
        if (t >= st) v += sb[pp][t - st];
        sb[pp ^ 1][t] = v;
        pp ^= 1;
        __syncthreads();
    }
    int bexcl = (t == 0) ? 0 : sb[pp][t - 1];
    lcur[t] = pcnt[t * NPB + blk] + bexcl;
    __syncthreads();
    int base4 = blk * (PCHUNK / 4);
    int n4 = min(PCHUNK / 4, N_EDGES / 4 - base4);
    const i32x4* s4 = (const i32x4*)ei;
    const i32x4* d4 = (const i32x4*)(ei + N_EDGES);
    for (int k = t; k < n4; k += 256) {
        i32x4 s = __builtin_nontemporal_load(s4 + base4 + k);
        i32x4 d = __builtin_nontemporal_load(d4 + base4 + k);
        int pos;
        pos = atomicAdd(&lcur[d.x >> BSHIFT], 1);
        ebuf[pos] = ((unsigned)s.x << BSHIFT) | (unsigned)(d.x & 511);
        pos = atomicAdd(&lcur[d.y >> BSHIFT], 1);
        ebuf[pos] = ((unsigned)s.y << BSHIFT) | (unsigned)(d.y & 511);
        pos = atomicAdd(&lcur[d.z >> BSHIFT], 1);
        ebuf[pos] = ((unsigned)s.z << BSHIFT) | (unsigned)(d.z & 511);
        pos = atomicAdd(&lcur[d.w >> BSHIFT], 1);
        ebuf[pos] = ((unsigned)s.w << BSHIFT) | (unsigned)(d.w & 511);
    }
}

// per-bucket local sort -> final CSR + off[] (x-gather removed: now in k_fused)
__global__ __launch_bounds__(512) void k_bfinal(const unsigned int* __restrict__ ebuf,
                                                const int* __restrict__ btot,
                                                int* __restrict__ off,
                                                int* __restrict__ csr)
{
    __shared__ int sb[2][256];
    __shared__ int cnt[512], scanbuf[2][512], cur[512];
    int tid = threadIdx.x, b = blockIdx.x;
    if (tid < 256) sb[0][tid] = (tid < NBUCK) ? btot[tid] : 0;
    __syncthreads();
    int pp = 0;
    for (int st = 1; st < 256; st <<= 1) {
        if (tid < 256) {
            int v = sb[pp][tid];
            if (tid >= st) v += sb[pp][tid - st];
            sb[pp ^ 1][tid] = v;
        }
        pp ^= 1;
        __syncthreads();
    }
    int base = (b == 0) ? 0 : sb[pp][b - 1];
    int nE = sb[pp][b] - base;
    if (b == NBUCK - 1 && tid == 0) off[N_NODES] = sb[pp][NBUCK - 1];
    cnt[tid] = 0;
    __syncthreads();
    for (int e = tid; e < nE; e += 512)
        atomicAdd(&cnt[ebuf[base + e] & 511], 1);
    __syncthreads();
    int p2 = 0;
    scanbuf[0][tid] = cnt[tid];
    __syncthreads();
    for (int st = 1; st < 512; st <<= 1) {
        int v = scanbuf[p2][tid];
        if (tid >= st) v += scanbuf[p2][tid - st];
        scanbuf[p2 ^ 1][tid] = v;
        p2 ^= 1;
        __syncthreads();
    }
    int excl = scanbuf[p2][tid] - cnt[tid];
    cur[tid] = excl;
    int gnode = (b << BSHIFT) + tid;
    if (gnode < N_NODES) off[gnode] = base + excl;
    __syncthreads();
    for (int e = tid; e < nE; e += 512) {
        unsigned int p = ebuf[base + e];
        int pos = atomicAdd(&cur[p & 511], 1);
        csr[base + pos] = (int)(p >> BSHIFT);
    }
}

// ---------------- fused GIN layer: L2-direct gather -> LDS transpose ->
//                  MFMA MLP -> z2 + BN stats.  512 thr / 64 nodes / block.
// Gather loads bypass L1 (agent-scope) so outstanding misses aren't capped by
// the L1 miss queue.  Layer 0: lane-per-edge parallel scalar x-gather.
__global__ __launch_bounds__(512, 8) void k_fused(
    const unsigned char* __restrict__ hq, const float* __restrict__ x,
    const int* __restrict__ off, const int* __restrict__ csr,
    const float* __restrict__ epsArr, const float* __restrict__ gamma,
    const float* __restrict__ beta, const float* __restrict__ W_enc,
    const float* __restrict__ b_enc, const float* __restrict__ W1,
    const float* __restrict__ b1, const float* __restrict__ W2,
    const float* __restrict__ b2, f16* __restrict__ z2out,
    float* __restrict__ stats, int layer)
{
    __shared__ f16 AT[64][40];           // stride 40: 16B-aligned, ~2-way banks
    __shared__ float T[4][16 * 36];
    __shared__ float redS[4][32], redQ[4][32];
    int tid = threadIdx.x, wave = tid >> 6, lane = tid & 63;
    int unit = tid >> 3, li = tid & 7;   // 64 nodes/block, 8 lanes/node
    int lbase = lane & 56;               // unit's lane-0 within wave
    int node = blockIdx.x * 64 + unit;
    int c0 = li * 4;                     // this lane's 4 channels

    if (node < N_NODES) {
        f16x4 r;
        if (layer == 0) {                // ---- lane-per-edge scalar x-gather
            int j0 = off[node], jend = off[node + 1];
            float S = 0.f;
            int jj = j0 + li;
            while (jj + 8 < jend) {      // 2 edges in flight per lane
                int i0 = __builtin_nontemporal_load(csr + jj);
                int i1 = __builtin_nontemporal_load(csr + jj + 8);
                unsigned xa = ld_l2_u32(x + i0);
                unsigned xb = ld_l2_u32(x + i1);
                S += __uint_as_float(xa) + __uint_as_float(xb);
                jj += 16;
            }
            if (jj < jend) {
                int i0 = __builtin_nontemporal_load(csr + jj);
                S += __uint_as_float(ld_l2_u32(x + i0));
            }
            S += __shfl_xor(S, 1);       // reduce across the 8-lane group
            S += __shfl_xor(S, 2);
            S += __shfl_xor(S, 4);
            float oneEps = 1.f + epsArr[0];
            float u  = fmaf(oneEps, x[node], S);
            float dv = oneEps + (float)(jend - j0);
            #pragma unroll
            for (int k = 0; k < 4; ++k)
                r[k] = (f16)(fmaf(u, W_enc[c0 + k], dv * b_enc[c0 + k]));
        } else {                         // ---- int8 gather, deep-pipelined
            const unsigned MASK = 0x00FF00FFu;
            const unsigned char* hql = hq + c0;
            int j = off[node], jend = off[node + 1];
            int navail = jend - j;
            unsigned qv = *(const unsigned*)(hql + ((unsigned)node << 5)); // self
            int ci0 = 0, ci1 = 0;
            if (li < navail)     ci0 = __builtin_nontemporal_load(csr + j + li);
            if (8 + li < navail) ci1 = __builtin_nontemporal_load(csr + j + 8 + li);
            unsigned a0 = 0, a1 = 0;
            while (navail >= 16) {
                unsigned g[16];
                #pragma unroll
                for (int e = 0; e < 8; ++e) {
                    int i0 = __shfl(ci0, lbase | e);
                    int i1 = __shfl(ci1, lbase | e);
                    g[e]     = ld_l2_u32(hql + ((unsigned)i0 << 5));
                    g[e + 8] = ld_l2_u32(hql + ((unsigned)i1 << 5));
                }
                j += 16; navail -= 16;   // prefetch next csr before the drain
                if (li < navail)     ci0 = __builtin_nontemporal_load(csr + j + li);
                if (8 + li < navail) ci1 = __builtin_nontemporal_load(csr + j + 8 + li);
                #pragma unroll
                for (int e = 0; e < 16; ++e) {
                    a0 += g[e] & MASK; a1 += (g[e] >> 8) & MASK;
                }
            }
            if (navail >= 8) {
                unsigned g[8];
                #pragma unroll
                for (int e = 0; e < 8; ++e) {
                    int i0 = __shfl(ci0, lbase | e);
                    g[e] = ld_l2_u32(hql + ((unsigned)i0 << 5));
                }
                ci0 = ci1; j += 8; navail -= 8;
                #pragma unroll
                for (int e = 0; e < 8; ++e) {
                    a0 += g[e] & MASK; a1 += (g[e] >> 8) & MASK;
                }
            }
            for (int e = 0; e < navail; ++e) {
                int i0 = __shfl(ci0, lbase | e);
                unsigned g = ld_l2_u32(hql + ((unsigned)i0 << 5));
                a0 += g & MASK; a1 += (g >> 8) & MASK;
            }
            // dequant: channels c0..c0+3
            float oneEps = 1.f + epsArr[layer];
            float F[4];
            F[0] = (float)(a0 & 0xFFFF); F[2] = (float)(a0 >> 16);
            F[1] = (float)(a1 & 0xFFFF); F[3] = (float)(a1 >> 16);
            #pragma unroll
            for (int k = 0; k < 4; ++k) {
                float g  = gamma[(layer - 1) * 32 + c0 + k];
                float bb = beta[(layer - 1) * 32 + c0 + k];
                float s  = fmaxf(fmaxf(bb + 5.5f * fabsf(g), 0.f), 1e-6f) / 255.f;
                float q  = (float)((qv >> (8 * k)) & 255u);
                r[k] = (f16)(s * (F[k] + oneEps * q));
            }
        }
        *(f16x4*)&AT[unit][c0] = r;      // LDS transpose write
    }
    __syncthreads();

    // ---- MFMA MLP: waves 0-3, one 16-node tile each ----
    int col = lane & 15, quad = lane >> 4;
    float sA = 0.f, qA = 0.f, sB = 0.f, qB = 0.f;
    int nb = blockIdx.x * 64 + wave * 16;
    if (wave < 4 && nb < N_NODES) {
        f16x8 a = *(const f16x8*)&AT[wave * 16 + col][quad * 8];
        const float* W1l = W1 + layer * 1024;
        const float* W2l = W2 + layer * 1024;
        f16x8 w1a, w1b, w2a, w2b;                    // B[k=quad*8+j][n=col(+16)]
        #pragma unroll
        for (int jj = 0; jj < 8; ++jj) {
            int k = quad * 8 + jj;
            w1a[jj] = (f16)W1l[k * 32 + col];
            w1b[jj] = (f16)W1l[k * 32 + col + 16];
            w2a[jj] = (f16)W2l[k * 32 + col];
            w2b[jj] = (f16)W2l[k * 32 + col + 16];
        }
        float b1a = b1[layer * 32 + col], b1b = b1[layer * 32 + col + 16];
        float b2a = b2[layer * 32 + col], b2b = b2[layer * 32 + col + 16];
        f32x4 bias1a = {b1a, b1a, b1a, b1a}, bias1b = {b1b, b1b, b1b, b1b};
        f32x4 bias2a = {b2a, b2a, b2a, b2a}, bias2b = {b2b, b2b, b2b, b2b};
        float* Tw = T[wave];

        f32x4 m0 = __builtin_amdgcn_mfma_f32_16x16x32_f16(a, w1a, bias1a, 0, 0, 0);
        f32x4 m1 = __builtin_amdgcn_mfma_f32_16x16x32_f16(a, w1b, bias1b, 0, 0, 0);
        #pragma unroll
        for (int rr = 0; rr < 4; ++rr) {             // relu + D-layout -> LDS
            int row = quad * 4 + rr;
            Tw[row * 36 + col]      = fmaxf(m0[rr], 0.f);
            Tw[row * 36 + col + 16] = fmaxf(m1[rr], 0.f);
        }
        f32x4 t0 = *(const f32x4*)(Tw + col * 36 + quad * 8);     // wave-sync
        f32x4 t1 = *(const f32x4*)(Tw + col * 36 + quad * 8 + 4);
        f16x8 a2;
        #pragma unroll
        for (int k = 0; k < 4; ++k) { a2[k] = (f16)t0[k]; a2[k + 4] = (f16)t1[k]; }
        f32x4 z0 = __builtin_amdgcn_mfma_f32_16x16x32_f16(a2, w2a, bias2a, 0, 0, 0);
        f32x4 zb = __builtin_amdgcn_mfma_f32_16x16x32_f16(a2, w2b, bias2b, 0, 0, 0);
        #pragma unroll
        for (int rr = 0; rr < 4; ++rr) {
            int n2 = nb + quad * 4 + rr;
            z2out[n2 * 32 + col]      = (f16)z0[rr];
            z2out[n2 * 32 + col + 16] = (f16)zb[rr];
            sA += z0[rr]; qA += z0[rr] * z0[rr];
            sB += zb[rr]; qB += zb[rr] * zb[rr];
        }
    }
    if (wave < 4) {
        sA += __shfl_xor(sA, 16); sA += __shfl_xor(sA, 32);
        qA += __shfl_xor(qA, 16); qA += __shfl_xor(qA, 32);
        sB += __shfl_xor(sB, 16); sB += __shfl_xor(sB, 32);
        qB += __shfl_xor(qB, 16); qB += __shfl_xor(qB, 32);
        if (lane < 16) {
            redS[wave][col] = sA; redS[wave][col + 16] = sB;
            redQ[wave][col] = qA; redQ[wave][col + 16] = qB;
        }
    }
    __syncthreads();
    if (tid < 64) {
        int sel = tid >> 5, cc = tid & 31;
        float s = 0.f;
        #pragma unroll
        for (int w = 0; w < 4; ++w) s += sel ? redQ[w][cc] : redS[w][cc];
        atomicAdd(&stats[layer * 64 + sel * 32 + cc], s);
    }
}

// ---------------- quantize: hq = uint8( relu(BN(z2)) / s )  -------------------
__global__ __launch_bounds__(256) void k_quant(
    const f16* __restrict__ z2, const float* __restrict__ stats,
    const float* __restrict__ gamma, const float* __restrict__ beta,
    unsigned char* __restrict__ hq, int layer)
{
    int idx = blockIdx.x * 256 + threadIdx.x;        // over N*4 (8 ch each)
    if (idx >= N_NODES * 4) return;
    int c0 = (idx & 3) * 8;
    const float invN = 1.0f / (float)N_NODES;
    float bnsc[8], bnsh[8], inv_s[8];
    #pragma unroll
    for (int k = 0; k < 8; ++k) {
        int ch = c0 + k;
        float g = gamma[layer * 32 + ch], bb = beta[layer * 32 + ch];
        float mu  = stats[layer * 64 + ch] * invN;
        float var = stats[layer * 64 + 32 + ch] * invN - mu * mu;
        float sc = g * rsqrtf(var + BN_EPS);
        bnsc[k] = sc;
        bnsh[k] = bb - mu * sc;
        float vmax = fmaxf(bb + 5.5f * fabsf(g), 0.f);
        inv_s[k] = 255.f / fmaxf(vmax, 1e-6f);       // matches k_fused dq_s
    }
    f16x8 z = *(const f16x8*)(z2 + (size_t)idx * 8);
    uc8 r;
    #pragma unroll
    for (int k = 0; k < 8; ++k) {
        float v = fmaxf(fmaf((float)z[k], bnsc[k], bnsh[k]), 0.f);
        int q = (int)(fminf(v * inv_s[k], 255.f) + 0.5f);
        r[k] = (unsigned char)q;
    }
    *(uc8*)(hq + (size_t)idx * 8) = r;               // keep hq in L2
}

// ---------------- global_add_pool with inline BN(3)+ReLU -----------------------
__global__ __launch_bounds__(256) void k_pool(const f16* __restrict__ z2,
                                              const int* __restrict__ batch,
                                              const float* __restrict__ stats,
                                              const float* __restrict__ gamma,
                                              const float* __restrict__ beta,
                                              float* __restrict__ pooled)
{
    int c = threadIdx.x & 31, slot = threadIdx.x >> 5;
    const float invN = 1.0f / (float)N_NODES;
    float mu  = stats[3 * 64 + c] * invN;
    float var = stats[3 * 64 + 32 + c] * invN - mu * mu;
    float sc = gamma[3 * 32 + c] * rsqrtf(var + BN_EPS);
    float sh = beta[3 * 32 + c] - mu * sc;
    int start = blockIdx.x * 256 + slot * 32;
    if (start >= N_NODES) return;
    int end = min(start + 32, N_NODES);
    int cur = batch[start]; float acc = 0.f;
    for (int i = start; i < end; ++i) {
        int g = batch[i];
        if (g != cur) { atomicAdd(&pooled[cur * HD + c], acc); acc = 0.f; cur = g; }
        acc += fmaxf(fmaf((float)z2[i * 32 + c], sc, sh), 0.f);
    }
    atomicAdd(&pooled[cur * HD + c], acc);
}

// ---------------- classifier ---------------------------------------------------
__global__ __launch_bounds__(256) void k_cls(const float* __restrict__ pooled,
                                             const float* __restrict__ Wc,
                                             const float* __restrict__ bc,
                                             float* __restrict__ out)
{
    int gid = blockIdx.x * 256 + threadIdx.x;
    if (gid >= NGRAPHS * 2) return;
    int g = gid >> 1, c = gid & 1;
    float s = bc[c];
    #pragma unroll
    for (int k = 0; k < 32; ++k) s = fmaf(pooled[g * 32 + k], Wc[k * 2 + c], s);
    out[gid] = s;
}

extern "C" void kernel_launch(void* const* d_in, const int* in_sizes, int n_in,
                              void* d_out, int out_size, void* d_ws, size_t ws_size,
                              hipStream_t stream)
{
    const float* x      = (const float*)d_in[0];
    const int*   ei     = (const int*)d_in[1];
    const int*   batch  = (const int*)d_in[2];
    const float* W_enc  = (const float*)d_in[3];
    const float* b_enc  = (const float*)d_in[4];
    const float* epsArr = (const float*)d_in[5];
    const float* W1     = (const float*)d_in[6];
    const float* b1     = (const float*)d_in[7];
    const float* W2     = (const float*)d_in[8];
    const float* b2     = (const float*)d_in[9];
    const float* gamma  = (const float*)d_in[10];
    const float* beta   = (const float*)d_in[11];
    const float* Wc     = (const float*)d_in[12];
    const float* bc     = (const float*)d_in[13];
    float* out = (float*)d_out;

    char* ws = (char*)d_ws;
    size_t o = 0;
    auto alloc = [&](size_t bytes) {
        char* p = ws + o;
        o += (bytes + 255) & ~(size_t)255;
        return p;
    };
    unsigned char* hq = (unsigned char*)alloc((size_t)N_NODES * 32);  // 3.2 MB
    f16*   z2     = (f16*) alloc((size_t)N_NODES * 32 * 2);    // 6.4 MB [node][32]
    int*   csr    = (int*) alloc((size_t)N_EDGES * 4);         // 12.8 MB
    unsigned int* ebuf = (unsigned int*)alloc((size_t)N_EDGES * 4);  // 12.8 MB
    int*   offA   = (int*) alloc((size_t)(N_NODES + 1) * 4);
    int*   pcnt   = (int*) alloc((size_t)256 * NPB * 4);       // 0.4 MB
    int*   btot   = (int*) alloc(1024);
    float* stats  = (float*)alloc(NLAYERS * 64 * 4);
    float* pooled = (float*)alloc((size_t)NGRAPHS * HD * 4);

    k_encphist<<<NPB + ZBLOCKS, 256, 0, stream>>>(ei, stats, pooled, pcnt);
    k_pscanA  <<<NBUCK, 512, 0, stream>>>(pcnt, btot);
    k_pscatter<<<NPB, 256, 0, stream>>>(ei, pcnt, btot, ebuf);
    k_bfinal  <<<NBUCK, 512, 0, stream>>>(ebuf, btot, offA, csr);

    for (int l = 0; l < NLAYERS; ++l) {
        k_fused<<<(N_NODES + 63) / 64, 512, 0, stream>>>(
            hq, x, offA, csr, epsArr, gamma, beta, W_enc, b_enc,
            W1, b1, W2, b2, z2, stats, l);
        if (l < NLAYERS - 1)
            k_quant<<<(N_NODES * 4 + 255) / 256, 256, 0, stream>>>(z2, stats,
                                                                   gamma, beta,
                                                                   hq, l);
    }
    k_pool<<<(N_NODES + 255) / 256, 256, 0, stream>>>(z2, batch, stats,
                                                      gamma, beta, pooled);
    k_cls <<<8, 256, 0, stream>>>(pooled, Wc, bc, out);
}

// Round 5
// 412.325 us; speedup vs baseline: 1.0750x; 1.0103x over previous
//
#include <hip/hip_runtime.h>

#define N_NODES 100000
#define N_EDGES 3200000
#define HD      32
#define NLAYERS 4
#define NGRAPHS 1000
#define BN_EPS  1e-5f
#define BSHIFT  9                         // 512-node buckets
#define NBUCK   ((N_NODES + 511) >> 9)    // 196
#define PCHUNK  8192                      // edges per partition block
#define NPB     ((N_EDGES + PCHUNK - 1) / PCHUNK)   // 391
#define ZBLOCKS ((NGRAPHS * HD + 255) / 256)        // 125

typedef _Float16 f16;
typedef _Float16 f16x4 __attribute__((ext_vector_type(4)));
typedef _Float16 f16x8 __attribute__((ext_vector_type(8)));
typedef float    f32x4 __attribute__((ext_vector_type(4)));
typedef int      i32x4 __attribute__((ext_vector_type(4)));
typedef unsigned int  u32x2 __attribute__((ext_vector_type(2)));
typedef unsigned char uc8 __attribute__((ext_vector_type(8)));

// L2-direct load (bypasses vector L1): agent-scope relaxed.
__device__ __forceinline__ unsigned ld_l2_u32(const void* p) {
    return __hip_atomic_load((const unsigned*)p, __ATOMIC_RELAXED,
                             __HIP_MEMORY_SCOPE_AGENT);
}

// ---------------- phist + zero stats/pooled ------------------------------------
__global__ __launch_bounds__(256) void k_encphist(
    const int* __restrict__ ei, float* __restrict__ stats,
    float* __restrict__ pooled, int* __restrict__ pcnt)
{
    __shared__ int hist[256];
    int bb = blockIdx.x, t = threadIdx.x;
    if (bb < NPB) {                                  // ---- phist part
        hist[t] = 0;
        __syncthreads();
        int base4 = bb * (PCHUNK / 4);
        int n4 = min(PCHUNK / 4, N_EDGES / 4 - base4);
        const i32x4* d4 = (const i32x4*)(ei + N_EDGES);
        for (int k = t; k < n4; k += 256) {
            i32x4 d = __builtin_nontemporal_load(d4 + base4 + k);
            atomicAdd(&hist[d.x >> BSHIFT], 1);
            atomicAdd(&hist[d.y >> BSHIFT], 1);
            atomicAdd(&hist[d.z >> BSHIFT], 1);
            atomicAdd(&hist[d.w >> BSHIFT], 1);
        }
        __syncthreads();
        pcnt[t * NPB + bb] = hist[t];
    } else {                                         // ---- zeroing part
        int gid = (bb - NPB) * 256 + t;
        if (gid < NLAYERS * 64)   stats[gid]  = 0.f;
        if (gid < NGRAPHS * HD)   pooled[gid] = 0.f;
    }
}

// per-bucket scan of per-block counts (in place) + bucket totals
__global__ __launch_bounds__(512) void k_pscanA(int* __restrict__ pcnt,
                                                int* __restrict__ btot)
{
    __shared__ int sc[2][512];
    int t = threadIdx.x, b = blockIdx.x;
    int base = b * NPB;
    int v = (t < NPB) ? pcnt[base + t] : 0;
    int pp = 0;
    sc[0][t] = v;
    __syncthreads();
    for (int st = 1; st < 512; st <<= 1) {
        int x = sc[pp][t];
        if (t >= st) x += sc[pp][t - st];
        sc[pp ^ 1][t] = x;
        pp ^= 1;
        __syncthreads();
    }
    int incl = sc[pp][t];
    if (t < NPB) pcnt[base + t] = incl - v;
    if (t == NPB - 1) btot[b] = incl;
}

// scatter packed edges (src<<9 | dstLocal) into dst-bucket regions
__global__ __launch_bounds__(256) void k_pscatter(const int* __restrict__ ei,
                                                  const int* __restrict__ pcnt,
                                                  const int* __restrict__ btot,
                                                  unsigned int* __restrict__ ebuf)
{
    __shared__ int sb[2][256];
    __shared__ int lcur[256];
    int t = threadIdx.x, blk = blockIdx.x;
    sb[0][t] = (t < NBUCK) ? btot[t] : 0;
    __syncthreads();
    int pp = 0;
    for (int st = 1; st < 256; st <<= 1) {
        int v = sb[pp][t];
        if (t >= st) v += sb[pp][t - st];
        sb[pp ^ 1][t] = v;
        pp ^= 1;
        __syncthreads();
    }
    int bexcl = (t == 0) ? 0 : sb[pp][t - 1];
    lcur[t] = pcnt[t * NPB + blk] + bexcl;
    __syncthreads();
    int base4 = blk * (PCHUNK / 4);
    int n4 = min(PCHUNK / 4, N_EDGES / 4 - base4);
    const i32x4* s4 = (const i32x4*)ei;
    const i32x4* d4 = (const i32x4*)(ei + N_EDGES);
    for (int k = t; k < n4; k += 256) {
        i32x4 s = __builtin_nontemporal_load(s4 + base4 + k);
        i32x4 d = __builtin_nontemporal_load(d4 + base4 + k);
        int pos;
        pos = atomicAdd(&lcur[d.x >> BSHIFT], 1);
        ebuf[pos] = ((unsigned)s.x << BSHIFT) | (unsigned)(d.x & 511);
        pos = atomicAdd(&lcur[d.y >> BSHIFT], 1);
        ebuf[pos] = ((unsigned)s.y << BSHIFT) | (unsigned)(d.y & 511);
        pos = atomicAdd(&lcur[d.z >> BSHIFT], 1);
        ebuf[pos] = ((unsigned)s.z << BSHIFT) | (unsigned)(d.z & 511);
        pos = atomicAdd(&lcur[d.w >> BSHIFT], 1);
        ebuf[pos] = ((unsigned)s.w << BSHIFT) | (unsigned)(d.w & 511);
    }
}

// per-bucket local sort -> final CSR + off[]
__global__ __launch_bounds__(512) void k_bfinal(const unsigned int* __restrict__ ebuf,
                                                const int* __restrict__ btot,
                                                int* __restrict__ off,
                                                int* __restrict__ csr)
{
    __shared__ int sb[2][256];
    __shared__ int cnt[512], scanbuf[2][512], cur[512];
    int tid = threadIdx.x, b = blockIdx.x;
    if (tid < 256) sb[0][tid] = (tid < NBUCK) ? btot[tid] : 0;
    __syncthreads();
    int pp = 0;
    for (int st = 1; st < 256; st <<= 1) {
        if (tid < 256) {
            int v = sb[pp][tid];
            if (tid >= st) v += sb[pp][tid - st];
            sb[pp ^ 1][tid] = v;
        }
        pp ^= 1;
        __syncthreads();
    }
    int base = (b == 0) ? 0 : sb[pp][b - 1];
    int nE = sb[pp][b] - base;
    if (b == NBUCK - 1 && tid == 0) off[N_NODES] = sb[pp][NBUCK - 1];
    cnt[tid] = 0;
    __syncthreads();
    for (int e = tid; e < nE; e += 512)
        atomicAdd(&cnt[ebuf[base + e] & 511], 1);
    __syncthreads();
    int p2 = 0;
    scanbuf[0][tid] = cnt[tid];
    __syncthreads();
    for (int st = 1; st < 512; st <<= 1) {
        int v = scanbuf[p2][tid];
        if (tid >= st) v += scanbuf[p2][tid - st];
        scanbuf[p2 ^ 1][tid] = v;
        p2 ^= 1;
        __syncthreads();
    }
    int excl = scanbuf[p2][tid] - cnt[tid];
    cur[tid] = excl;
    int gnode = (b << BSHIFT) + tid;
    if (gnode < N_NODES) off[gnode] = base + excl;
    __syncthreads();
    for (int e = tid; e < nE; e += 512) {
        unsigned int p = ebuf[base + e];
        int pos = atomicAdd(&cur[p & 511], 1);
        csr[base + pos] = (int)(p >> BSHIFT);
    }
}

// ---------------- fused GIN layer: ping-pong-pipelined gather -> LDS transpose
//                  -> MFMA MLP -> z2 + BN stats.  512 thr / 64 nodes / block.
// Gather keeps one 16-load batch ALWAYS in flight while the other drains
// (g/h register double-buffer) — no per-iteration vmcnt(0) sawtooth.
__global__ __launch_bounds__(512, 6) void k_fused(
    const unsigned char* __restrict__ hq, const float* __restrict__ x,
    const int* __restrict__ off, const int* __restrict__ csr,
    const float* __restrict__ epsArr, const float* __restrict__ gamma,
    const float* __restrict__ beta, const float* __restrict__ W_enc,
    const float* __restrict__ b_enc, const float* __restrict__ W1,
    const float* __restrict__ b1, const float* __restrict__ W2,
    const float* __restrict__ b2, f16* __restrict__ z2out,
    float* __restrict__ stats, int layer)
{
    __shared__ f16 AT[64][40];           // stride 40: 16B-aligned, ~2-way banks
    __shared__ float T[4][16 * 36];
    __shared__ float redS[4][32], redQ[4][32];
    int tid = threadIdx.x, wave = tid >> 6, lane = tid & 63;
    int unit = tid >> 3, li = tid & 7;   // 64 nodes/block, 8 lanes/node
    int lbase = lane & 56;               // unit's lane-0 within wave
    int node = blockIdx.x * 64 + unit;
    int c0 = li * 4;                     // this lane's 4 channels

    if (node < N_NODES) {
        f16x4 r;
        if (layer == 0) {                // ---- lane-per-edge scalar x-gather
            int j0 = off[node], jend = off[node + 1];
            float S = 0.f;
            int jj = j0 + li;
            while (jj + 8 < jend) {      // 2 edges in flight per lane
                int i0 = __builtin_nontemporal_load(csr + jj);
                int i1 = __builtin_nontemporal_load(csr + jj + 8);
                unsigned xa = ld_l2_u32(x + i0);
                unsigned xb = ld_l2_u32(x + i1);
                S += __uint_as_float(xa) + __uint_as_float(xb);
                jj += 16;
            }
            if (jj < jend) {
                int i0 = __builtin_nontemporal_load(csr + jj);
                S += __uint_as_float(ld_l2_u32(x + i0));
            }
            S += __shfl_xor(S, 1);       // reduce across the 8-lane group
            S += __shfl_xor(S, 2);
            S += __shfl_xor(S, 4);
            float oneEps = 1.f + epsArr[0];
            float u  = fmaf(oneEps, x[node], S);
            float dv = oneEps + (float)(jend - j0);
            #pragma unroll
            for (int k = 0; k < 4; ++k)
                r[k] = (f16)(fmaf(u, W_enc[c0 + k], dv * b_enc[c0 + k]));
        } else {                         // ---- int8 gather, ping-pong pipeline
            const unsigned MASK = 0x00FF00FFu;
            const unsigned char* hql = hq + c0;
            int j0 = off[node], jend = off[node + 1];
            int total = jend - j0;
            int nb = total >> 4, tail = total & 15;
            unsigned qv = *(const unsigned*)(hql + ((unsigned)node << 5)); // self
            unsigned a0 = 0, a1 = 0;
            int jn = j0;
            int ci0 = 0, ci1 = 0;
            auto LOADCI = [&](int n) {
                ci0 = (li < n)     ? __builtin_nontemporal_load(csr + jn + li)     : 0;
                ci1 = (8 + li < n) ? __builtin_nontemporal_load(csr + jn + 8 + li) : 0;
            };
            auto ISSUE = [&](unsigned* G) {
                #pragma unroll
                for (int e = 0; e < 8; ++e) {
                    int i0 = __shfl(ci0, lbase | e);
                    int i1 = __shfl(ci1, lbase | e);
                    G[e]     = ld_l2_u32(hql + ((unsigned)i0 << 5));
                    G[e + 8] = ld_l2_u32(hql + ((unsigned)i1 << 5));
                }
                jn += 16;
            };
            auto ACCUM = [&](const unsigned* G) {
                #pragma unroll
                for (int e = 0; e < 16; ++e) {
                    a0 += G[e] & MASK; a1 += (G[e] >> 8) & MASK;
                }
            };
            unsigned g[16], h[16];
            LOADCI(nb > 0 ? 16 : tail);
            if (nb > 0) {
                ISSUE(g);
                int rem = nb - 1;                // batches not yet issued
                LOADCI(rem >= 1 ? 16 : tail);
                while (rem >= 2) {
                    ISSUE(h); --rem; LOADCI(rem >= 1 ? 16 : tail);
                    ACCUM(g);                    // h stays in flight
                    ISSUE(g); --rem; LOADCI(rem >= 1 ? 16 : tail);
                    ACCUM(h);                    // g stays in flight
                }
                if (rem == 1) {
                    ISSUE(h); LOADCI(tail);
                    ACCUM(g);
                    ACCUM(h);
                } else {
                    ACCUM(g);
                }
            }
            for (int e = 0; e < tail; ++e) {     // tail (<16 edges)
                int idx = __shfl((e < 8) ? ci0 : ci1, lbase | (e & 7));
                unsigned gg = ld_l2_u32(hql + ((unsigned)idx << 5));
                a0 += gg & MASK; a1 += (gg >> 8) & MASK;
            }
            // dequant: channels c0..c0+3
            float oneEps = 1.f + epsArr[layer];
            float F[4];
            F[0] = (float)(a0 & 0xFFFF); F[2] = (float)(a0 >> 16);
            F[1] = (float)(a1 & 0xFFFF); F[3] = (float)(a1 >> 16);
            #pragma unroll
            for (int k = 0; k < 4; ++k) {
                float gm = gamma[(layer - 1) * 32 + c0 + k];
                float bb = beta[(layer - 1) * 32 + c0 + k];
                float s  = fmaxf(fmaxf(bb + 5.5f * fabsf(gm), 0.f), 1e-6f) / 255.f;
                float q  = (float)((qv >> (8 * k)) & 255u);
                r[k] = (f16)(s * (F[k] + oneEps * q));
            }
        }
        *(f16x4*)&AT[unit][c0] = r;      // LDS transpose write
    }
    __syncthreads();

    // ---- MFMA MLP: waves 0-3, one 16-node tile each ----
    int col = lane & 15, quad = lane >> 4;
    float sA = 0.f, qA = 0.f, sB = 0.f, qB = 0.f;
    int nb2 = blockIdx.x * 64 + wave * 16;
    if (wave < 4 && nb2 < N_NODES) {
        f16x8 a = *(const f16x8*)&AT[wave * 16 + col][quad * 8];
        const float* W1l = W1 + layer * 1024;
        const float* W2l = W2 + layer * 1024;
        f16x8 w1a, w1b, w2a, w2b;                    // B[k=quad*8+j][n=col(+16)]
        #pragma unroll
        for (int jj = 0; jj < 8; ++jj) {
            int k = quad * 8 + jj;
            w1a[jj] = (f16)W1l[k * 32 + col];
            w1b[jj] = (f16)W1l[k * 32 + col + 16];
            w2a[jj] = (f16)W2l[k * 32 + col];
            w2b[jj] = (f16)W2l[k * 32 + col + 16];
        }
        float b1a = b1[layer * 32 + col], b1b = b1[layer * 32 + col + 16];
        float b2a = b2[layer * 32 + col], b2b = b2[layer * 32 + col + 16];
        f32x4 bias1a = {b1a, b1a, b1a, b1a}, bias1b = {b1b, b1b, b1b, b1b};
        f32x4 bias2a = {b2a, b2a, b2a, b2a}, bias2b = {b2b, b2b, b2b, b2b};
        float* Tw = T[wave];

        f32x4 m0 = __builtin_amdgcn_mfma_f32_16x16x32_f16(a, w1a, bias1a, 0, 0, 0);
        f32x4 m1 = __builtin_amdgcn_mfma_f32_16x16x32_f16(a, w1b, bias1b, 0, 0, 0);
        #pragma unroll
        for (int rr = 0; rr < 4; ++rr) {             // relu + D-layout -> LDS
            int row = quad * 4 + rr;
            Tw[row * 36 + col]      = fmaxf(m0[rr], 0.f);
            Tw[row * 36 + col + 16] = fmaxf(m1[rr], 0.f);
        }
        f32x4 t0 = *(const f32x4*)(Tw + col * 36 + quad * 8);     // wave-sync
        f32x4 t1 = *(const f32x4*)(Tw + col * 36 + quad * 8 + 4);
        f16x8 a2;
        #pragma unroll
        for (int k = 0; k < 4; ++k) { a2[k] = (f16)t0[k]; a2[k + 4] = (f16)t1[k]; }
        f32x4 z0 = __builtin_amdgcn_mfma_f32_16x16x32_f16(a2, w2a, bias2a, 0, 0, 0);
        f32x4 zb = __builtin_amdgcn_mfma_f32_16x16x32_f16(a2, w2b, bias2b, 0, 0, 0);
        #pragma unroll
        for (int rr = 0; rr < 4; ++rr) {
            int n2 = nb2 + quad * 4 + rr;
            z2out[n2 * 32 + col]      = (f16)z0[rr];
            z2out[n2 * 32 + col + 16] = (f16)zb[rr];
            sA += z0[rr]; qA += z0[rr] * z0[rr];
            sB += zb[rr]; qB += zb[rr] * zb[rr];
        }
    }
    if (wave < 4) {
        sA += __shfl_xor(sA, 16); sA += __shfl_xor(sA, 32);
        qA += __shfl_xor(qA, 16); qA += __shfl_xor(qA, 32);
        sB += __shfl_xor(sB, 16); sB += __shfl_xor(sB, 32);
        qB += __shfl_xor(qB, 16); qB += __shfl_xor(qB, 32);
        if (lane < 16) {
            redS[wave][col] = sA; redS[wave][col + 16] = sB;
            redQ[wave][col] = qA; redQ[wave][col + 16] = qB;
        }
    }
    __syncthreads();
    if (tid < 64) {
        int sel = tid >> 5, cc = tid & 31;
        float s = 0.f;
        #pragma unroll
        for (int w = 0; w < 4; ++w) s += sel ? redQ[w][cc] : redS[w][cc];
        atomicAdd(&stats[layer * 64 + sel * 32 + cc], s);
    }
}

// ---------------- quantize: hq = uint8( relu(BN(z2)) / s )  -------------------
__global__ __launch_bounds__(256) void k_quant(
    const f16* __restrict__ z2, const float* __restrict__ stats,
    const float* __restrict__ gamma, const float* __restrict__ beta,
    unsigned char* __restrict__ hq, int layer)
{
    int idx = blockIdx.x * 256 + threadIdx.x;        // over N*4 (8 ch each)
    if (idx >= N_NODES * 4) return;
    int c0 = (idx & 3) * 8;
    const float invN = 1.0f / (float)N_NODES;
    float bnsc[8], bnsh[8], inv_s[8];
    #pragma unroll
    for (int k = 0; k < 8; ++k) {
        int ch = c0 + k;
        float g = gamma[layer * 32 + ch], bb = beta[layer * 32 + ch];
        float mu  = stats[layer * 64 + ch] * invN;
        float var = stats[layer * 64 + 32 + ch] * invN - mu * mu;
        float sc = g * rsqrtf(var + BN_EPS);
        bnsc[k] = sc;
        bnsh[k] = bb - mu * sc;
        float vmax = fmaxf(bb + 5.5f * fabsf(g), 0.f);
        inv_s[k] = 255.f / fmaxf(vmax, 1e-6f);       // matches k_fused dq_s
    }
    f16x8 z = *(const f16x8*)(z2 + (size_t)idx * 8);
    uc8 r;
    #pragma unroll
    for (int k = 0; k < 8; ++k) {
        float v = fmaxf(fmaf((float)z[k], bnsc[k], bnsh[k]), 0.f);
        int q = (int)(fminf(v * inv_s[k], 255.f) + 0.5f);
        r[k] = (unsigned char)q;
    }
    *(uc8*)(hq + (size_t)idx * 8) = r;               // keep hq in L2
}

// ---------------- global_add_pool with inline BN(3)+ReLU -----------------------
__global__ __launch_bounds__(256) void k_pool(const f16* __restrict__ z2,
                                              const int* __restrict__ batch,
                                              const float* __restrict__ stats,
                                              const float* __restrict__ gamma,
                                              const float* __restrict__ beta,
                                              float* __restrict__ pooled)
{
    int c = threadIdx.x & 31, slot = threadIdx.x >> 5;
    const float invN = 1.0f / (float)N_NODES;
    float mu  = stats[3 * 64 + c] * invN;
    float var = stats[3 * 64 + 32 + c] * invN - mu * mu;
    float sc = gamma[3 * 32 + c] * rsqrtf(var + BN_EPS);
    float sh = beta[3 * 32 + c] - mu * sc;
    int start = blockIdx.x * 256 + slot * 32;
    if (start >= N_NODES) return;
    int end = min(start + 32, N_NODES);
    int cur = batch[start]; float acc = 0.f;
    for (int i = start; i < end; ++i) {
        int g = batch[i];
        if (g != cur) { atomicAdd(&pooled[cur * HD + c], acc); acc = 0.f; cur = g; }
        acc += fmaxf(fmaf((float)z2[i * 32 + c], sc, sh), 0.f);
    }
    atomicAdd(&pooled[cur * HD + c], acc);
}

// ---------------- classifier ---------------------------------------------------
__global__ __launch_bounds__(256) void k_cls(const float* __restrict__ pooled,
                                             const float* __restrict__ Wc,
                                             const float* __restrict__ bc,
                                             float* __restrict__ out)
{
    int gid = blockIdx.x * 256 + threadIdx.x;
    if (gid >= NGRAPHS * 2) return;
    int g = gid >> 1, c = gid & 1;
    float s = bc[c];
    #pragma unroll
    for (int k = 0; k < 32; ++k) s = fmaf(pooled[g * 32 + k], Wc[k * 2 + c], s);
    out[gid] = s;
}

extern "C" void kernel_launch(void* const* d_in, const int* in_sizes, int n_in,
                              void* d_out, int out_size, void* d_ws, size_t ws_size,
                              hipStream_t stream)
{
    const float* x      = (const float*)d_in[0];
    const int*   ei     = (const int*)d_in[1];
    const int*   batch  = (const int*)d_in[2];
    const float* W_enc  = (const float*)d_in[3];
    const float* b_enc  = (const float*)d_in[4];
    const float* epsArr = (const float*)d_in[5];
    const float* W1     = (const float*)d_in[6];
    const float* b1     = (const float*)d_in[7];
    const float* W2     = (const float*)d_in[8];
    const float* b2     = (const float*)d_in[9];
    const float* gamma  = (const float*)d_in[10];
    const float* beta   = (const float*)d_in[11];
    const float* Wc     = (const float*)d_in[12];
    const float* bc     = (const float*)d_in[13];
    float* out = (float*)d_out;

    char* ws = (char*)d_ws;
    size_t o = 0;
    auto alloc = [&](size_t bytes) {
        char* p = ws + o;
        o += (bytes + 255) & ~(size_t)255;
        return p;
    };
    unsigned char* hq = (unsigned char*)alloc((size_t)N_NODES * 32);  // 3.2 MB
    f16*   z2     = (f16*) alloc((size_t)N_NODES * 32 * 2);    // 6.4 MB [node][32]
    int*   csr    = (int*) alloc((size_t)N_EDGES * 4);         // 12.8 MB
    unsigned int* ebuf = (unsigned int*)alloc((size_t)N_EDGES * 4);  // 12.8 MB
    int*   offA   = (int*) alloc((size_t)(N_NODES + 1) * 4);
    int*   pcnt   = (int*) alloc((size_t)256 * NPB * 4);       // 0.4 MB
    int*   btot   = (int*) alloc(1024);
    float* stats  = (float*)alloc(NLAYERS * 64 * 4);
    float* pooled = (float*)alloc((size_t)NGRAPHS * HD * 4);

    k_encphist<<<NPB + ZBLOCKS, 256, 0, stream>>>(ei, stats, pooled, pcnt);
    k_pscanA  <<<NBUCK, 512, 0, stream>>>(pcnt, btot);
    k_pscatter<<<NPB, 256, 0, stream>>>(ei, pcnt, btot, ebuf);
    k_bfinal  <<<NBUCK, 512, 0, stream>>>(ebuf, btot, offA, csr);

    for (int l = 0; l < NLAYERS; ++l) {
        k_fused<<<(N_NODES + 63) / 64, 512, 0, stream>>>(
            hq, x, offA, csr, epsArr, gamma, beta, W_enc, b_enc,
            W1, b1, W2, b2, z2, stats, l);
        if (l < NLAYERS - 1)
            k_quant<<<(N_NODES * 4 + 255) / 256, 256, 0, stream>>>(z2, stats,
                                                                   gamma, beta,
                                                                   hq, l);
    }
    k_pool<<<(N_NODES + 255) / 256, 256, 0, stream>>>(z2, batch, stats,
                                                      gamma, beta, pooled);
    k_cls <<<8, 256, 0, stream>>>(pooled, Wc, bc, out);
}